// Round 7
// baseline (60.016 us; speedup 1.0000x reference)
//
#include <hip/hip_runtime.h>

// y[n][r] = sum_c weights[weight_idx[n]][r][c] * values[input_idx[n]][c]
// N=2M, M=2M, U=1024, R=C=8, f32.
// Persistent 256 blocks x 1024 threads, weights staged once to LDS as f16
// (row-rotation swizzled). NPT=8 -> T*NPT >= N: single batch per thread with
// 16 independent gathers in flight (max MLP test vs fabric ceiling).

typedef float f32x4 __attribute__((ext_vector_type(4)));
typedef unsigned int u32;
typedef u32 u32x4 __attribute__((ext_vector_type(4)));
typedef __fp16 f16x2 __attribute__((ext_vector_type(2)));

#define NPT    8
#define BLOCK  1024
#define GRID   256
#define U_MATS 1024

union HU { u32 u; f16x2 h; };

__global__ __launch_bounds__(BLOCK) void neuron_gemv_kernel(
    const f32x4* __restrict__ values,   // [M][2] as f32x4
    const f32x4* __restrict__ weights,  // [U][16] as f32x4
    const int*   __restrict__ input_idx,
    const int*   __restrict__ weight_idx,
    f32x4*       __restrict__ out,      // [N][2] as f32x4
    int N)
{
    // f16 weight table, row-rotated swizzle: matrix u, logical row r ->
    // u32 offset u*32 + ((r+u)&7)*4
    __shared__ u32 wlds[U_MATS * 32];   // 128 KB -> 1 block/CU

    for (int g = threadIdx.x; g < U_MATS * 16; g += BLOCK) {
        f32x4 v = weights[g];
        int u = g >> 4;
        int e = g & 15;
        int r = e >> 1;
        int h = e & 1;
        int dst = u * 32 + (((r + u) & 7) << 2) + h * 2;
        HU a, b;
        a.h = f16x2{(__fp16)v.x, (__fp16)v.y};
        b.h = f16x2{(__fp16)v.z, (__fp16)v.w};
        wlds[dst + 0] = a.u;
        wlds[dst + 1] = b.u;
    }
    __syncthreads();

    const u32x4* wl4 = (const u32x4*)wlds;  // row r of mat u at wl4[u*8 + ((r+u)&7)]

    const int T   = GRID * BLOCK;           // 262144 threads; T*NPT = 2.097M >= N
    const int tid = blockIdx.x * BLOCK + threadIdx.x;

    // Batch idx loads (coalesced, independent)
    int ii[NPT], wi[NPT];
#pragma unroll
    for (int j = 0; j < NPT; ++j) {
        int n  = tid + j * T;
        int nc = (n < N) ? n : 0;
        ii[j] = input_idx[nc];
        wi[j] = weight_idx[nc];
    }

    // Issue all 16 gathers (independent, fill the vmcnt queue)
    f32x4 x0[NPT], x1[NPT];
#pragma unroll
    for (int j = 0; j < NPT; ++j) {
        x0[j] = values[(size_t)ii[j] * 2 + 0];
        x1[j] = values[(size_t)ii[j] * 2 + 1];
    }

    // Compute from LDS weights + store
#pragma unroll
    for (int j = 0; j < NPT; ++j) {
        int n = tid + j * T;
        if (n >= N) continue;
        int b   = wi[j] * 8;
        int rot = wi[j] & 7;
        float y[8];
#pragma unroll
        for (int r = 0; r < 8; ++r) {
            u32x4 wr = wl4[b + ((r + rot) & 7)];
            HU p0, p1, p2, p3;
            p0.u = wr.x; p1.u = wr.y; p2.u = wr.z; p3.u = wr.w;
            y[r] = (float)p0.h.x * x0[j].x + (float)p0.h.y * x0[j].y
                 + (float)p1.h.x * x0[j].z + (float)p1.h.y * x0[j].w
                 + (float)p2.h.x * x1[j].x + (float)p2.h.y * x1[j].y
                 + (float)p3.h.x * x1[j].z + (float)p3.h.y * x1[j].w;
        }
        f32x4 o0 = { y[0], y[1], y[2], y[3] };
        f32x4 o1 = { y[4], y[5], y[6], y[7] };
        out[(size_t)n * 2 + 0] = o0;
        out[(size_t)n * 2 + 1] = o1;
    }
}

extern "C" void kernel_launch(void* const* d_in, const int* in_sizes, int n_in,
                              void* d_out, int out_size, void* d_ws, size_t ws_size,
                              hipStream_t stream) {
    const f32x4* values  = (const f32x4*)d_in[0];
    const f32x4* weights = (const f32x4*)d_in[1];
    const int*   iidx    = (const int*)d_in[2];
    const int*   widx    = (const int*)d_in[3];
    f32x4*       out     = (f32x4*)d_out;

    int N = in_sizes[2];  // input_idx element count

    neuron_gemv_kernel<<<GRID, BLOCK, 0, stream>>>(values, weights, iidx, widx, out, N);
}

// Round 8
// 59.141 us; speedup vs baseline: 1.0148x; 1.0148x over previous
//
#include <hip/hip_runtime.h>

// y[n][r] = sum_c weights[weight_idx[n]][r][c] * values[input_idx[n]][c]
// N=2M, M=2M, U=1024, R=C=8, f32.
// BEST CONFIG (R6): persistent 256 blocks x 1024 threads (1 block/CU via
// 128 KB LDS), weights staged once to LDS as f16 (row-rotation swizzled),
// grid-stride NPT=4 batches with pipelined index prefetch.
// Random-gather EA path saturates at ~3.15 TB/s (64 B sector, ~1/2 streaming
// efficiency) -> ~59 us structural floor for this access pattern.

typedef float f32x4 __attribute__((ext_vector_type(4)));
typedef unsigned int u32;
typedef u32 u32x4 __attribute__((ext_vector_type(4)));
typedef __fp16 f16x2 __attribute__((ext_vector_type(2)));

#define NPT    4
#define BLOCK  1024
#define GRID   256
#define U_MATS 1024

union HU { u32 u; f16x2 h; };

__global__ __launch_bounds__(BLOCK) void neuron_gemv_kernel(
    const f32x4* __restrict__ values,   // [M][2] as f32x4
    const f32x4* __restrict__ weights,  // [U][16] as f32x4
    const int*   __restrict__ input_idx,
    const int*   __restrict__ weight_idx,
    f32x4*       __restrict__ out,      // [N][2] as f32x4
    int N)
{
    // f16 weight table, row-rotated swizzle: matrix u, logical row r ->
    // u32 offset u*32 + ((r+u)&7)*4  (spreads divergent ds_read_b128 over banks)
    __shared__ u32 wlds[U_MATS * 32];   // 128 KB -> 1 block/CU

    for (int g = threadIdx.x; g < U_MATS * 16; g += BLOCK) {
        f32x4 v = weights[g];
        int u = g >> 4;
        int e = g & 15;
        int r = e >> 1;
        int h = e & 1;
        int dst = u * 32 + (((r + u) & 7) << 2) + h * 2;
        HU a, b;
        a.h = f16x2{(__fp16)v.x, (__fp16)v.y};
        b.h = f16x2{(__fp16)v.z, (__fp16)v.w};
        wlds[dst + 0] = a.u;
        wlds[dst + 1] = b.u;
    }
    __syncthreads();

    const u32x4* wl4 = (const u32x4*)wlds;  // row r of mat u at wl4[u*8 + ((r+u)&7)]

    const int  T   = GRID * BLOCK;          // 262144 threads
    const int  tid = blockIdx.x * BLOCK + threadIdx.x;

    int ii[NPT], wi[NPT], iin[NPT], win[NPT];

    // Prologue: indices for first batch
    long base = tid;
#pragma unroll
    for (int j = 0; j < NPT; ++j) {
        long n  = base + (long)j * T;
        int  nc = (n < N) ? (int)n : 0;
        ii[j] = input_idx[nc];
        wi[j] = weight_idx[nc];
    }

    while (base < N) {
        long nextbase = base + (long)T * NPT;

        // Issue all gathers for current batch (independent, fill vmcnt queue)
        f32x4 x0[NPT], x1[NPT];
#pragma unroll
        for (int j = 0; j < NPT; ++j) {
            x0[j] = values[(size_t)ii[j] * 2 + 0];
            x1[j] = values[(size_t)ii[j] * 2 + 1];
        }

        // Prefetch next batch's indices BEFORE consuming gathers:
        // their latency hides under this batch's compute.
        if (nextbase < N) {
#pragma unroll
            for (int j = 0; j < NPT; ++j) {
                long n  = nextbase + (long)j * T;
                int  nc = (n < N) ? (int)n : 0;
                iin[j] = input_idx[nc];
                win[j] = weight_idx[nc];
            }
        }

        // Compute from LDS weights + store
#pragma unroll
        for (int j = 0; j < NPT; ++j) {
            long n = base + (long)j * T;
            if (n >= N) continue;
            int b   = wi[j] * 8;
            int rot = wi[j] & 7;
            float y[8];
#pragma unroll
            for (int r = 0; r < 8; ++r) {
                u32x4 wr = wl4[b + ((r + rot) & 7)];
                HU p0, p1, p2, p3;
                p0.u = wr.x; p1.u = wr.y; p2.u = wr.z; p3.u = wr.w;
                y[r] = (float)p0.h.x * x0[j].x + (float)p0.h.y * x0[j].y
                     + (float)p1.h.x * x0[j].z + (float)p1.h.y * x0[j].w
                     + (float)p2.h.x * x1[j].x + (float)p2.h.y * x1[j].y
                     + (float)p3.h.x * x1[j].z + (float)p3.h.y * x1[j].w;
            }
            f32x4 o0 = { y[0], y[1], y[2], y[3] };
            f32x4 o1 = { y[4], y[5], y[6], y[7] };
            out[(size_t)n * 2 + 0] = o0;
            out[(size_t)n * 2 + 1] = o1;
        }

        base = nextbase;
#pragma unroll
        for (int j = 0; j < NPT; ++j) { ii[j] = iin[j]; wi[j] = win[j]; }
    }
}

extern "C" void kernel_launch(void* const* d_in, const int* in_sizes, int n_in,
                              void* d_out, int out_size, void* d_ws, size_t ws_size,
                              hipStream_t stream) {
    const f32x4* values  = (const f32x4*)d_in[0];
    const f32x4* weights = (const f32x4*)d_in[1];
    const int*   iidx    = (const int*)d_in[2];
    const int*   widx    = (const int*)d_in[3];
    f32x4*       out     = (f32x4*)d_out;

    int N = in_sizes[2];  // input_idx element count

    neuron_gemv_kernel<<<GRID, BLOCK, 0, stream>>>(values, weights, iidx, widx, out, N);
}